// Round 1
// baseline (629.816 us; speedup 1.0000x reference)
//
#include <hip/hip_runtime.h>
#include <hip/hip_bf16.h>
#include <cstddef>

#define T_DIM 2048
#define D_DIM 1024
#define GAMMA_F 0.96875f

// ---------------------------------------------------------------------------
// K0: wv_sum[i] = sum_d Wv[i][d]            (Wv: [1024,1024] row-major)
// ---------------------------------------------------------------------------
__global__ __launch_bounds__(256) void k_wvsum(const float* __restrict__ Wv,
                                               float* __restrict__ wv_sum) {
    __shared__ float red[4];
    const int i = blockIdx.x;
    const int tid = threadIdx.x;
    const float* row = Wv + (size_t)i * D_DIM;
    float p = 0.f;
    for (int c = tid; c < D_DIM; c += 256) p += row[c];
    for (int o = 32; o; o >>= 1) p += __shfl_down(p, o);
    if ((tid & 63) == 0) red[tid >> 6] = p;
    __syncthreads();
    if (tid == 0) wv_sum[i] = red[0] + red[1] + red[2] + red[3];
}

// ---------------------------------------------------------------------------
// K1: per t: vsum[b] = x[b,t,:] . wv_sum;  y[t,i] = sum_b x[b,t,i]*vsum[b]
// One pass over x (32 MB). Grid = T blocks of 256 threads. B hardcoded 4.
// ---------------------------------------------------------------------------
__global__ __launch_bounds__(256) void k_vsum_y(const float* __restrict__ x,
                                                const float* __restrict__ wv_sum,
                                                float* __restrict__ y) {
    __shared__ float xs[4][D_DIM];
    __shared__ float red[4][4];   // [wave][b]
    const int t = blockIdx.x;
    const int tid = threadIdx.x;
    const int lane = tid & 63, wv = tid >> 6;

    #pragma unroll
    for (int b = 0; b < 4; ++b) {
        const float* xr = x + ((size_t)b * T_DIM + t) * D_DIM;
        for (int c = tid; c < D_DIM; c += 256) xs[b][c] = xr[c];
    }
    __syncthreads();

    #pragma unroll
    for (int b = 0; b < 4; ++b) {
        float p = 0.f;
        for (int c = tid; c < D_DIM; c += 256) p += xs[b][c] * wv_sum[c];
        for (int o = 32; o; o >>= 1) p += __shfl_down(p, o);
        if (lane == 0) red[wv][b] = p;
    }
    __syncthreads();

    float vs[4];
    #pragma unroll
    for (int b = 0; b < 4; ++b)
        vs[b] = red[0][b] + red[1][b] + red[2][b] + red[3][b];

    for (int i = tid; i < D_DIM; i += 256) {
        float acc = 0.f;
        #pragma unroll
        for (int b = 0; b < 4; ++b) acc += xs[b][i] * vs[b];
        y[(size_t)t * D_DIM + i] = acc;
    }
}

// ---------------------------------------------------------------------------
// K2: tiled fp32 GEMM  C[M,1024] = A[M,1024] @ Bm[1024,1024]
// 64x64 tile, BK=16, 256 threads, 4x4 per-thread micro-tile.
// EPI=1: fuse the scramble-multiply epilogue:
//   out[r,d] = acc * S[2d + (t>>10)][t&1023],  t = r & 2047
// ---------------------------------------------------------------------------
template <int EPI>
__global__ __launch_bounds__(256) void k_gemm(const float* __restrict__ A,
                                              const float* __restrict__ Bm,
                                              float* __restrict__ C,
                                              const float* __restrict__ S) {
    __shared__ float As[16][68];   // [k][row], padded
    __shared__ float Bs[16][68];   // [k][col], padded

    const int tid = threadIdx.x;
    const int tx = tid & 15, ty = tid >> 4;
    const int rowBase = blockIdx.x * 64;
    const int colBase = blockIdx.y * 64;

    const int aK = tid & 15, aR = tid >> 4;   // A: col aK, rows aR+16q
    const int bN = tid & 63, bK = tid >> 6;   // B: col bN, rows bK+4q

    float acc[4][4] = {};

    for (int kb = 0; kb < 1024; kb += 16) {
        #pragma unroll
        for (int q = 0; q < 4; ++q) {
            As[aK][aR + 16 * q] =
                A[(size_t)(rowBase + aR + 16 * q) * 1024 + kb + aK];
            Bs[bK + 4 * q][bN] =
                Bm[(size_t)(kb + bK + 4 * q) * 1024 + colBase + bN];
        }
        __syncthreads();
        #pragma unroll
        for (int kk = 0; kk < 16; ++kk) {
            float4 av = *(const float4*)&As[kk][ty * 4];
            float4 bv = *(const float4*)&Bs[kk][tx * 4];
            float a_[4] = {av.x, av.y, av.z, av.w};
            float b_[4] = {bv.x, bv.y, bv.z, bv.w};
            #pragma unroll
            for (int i2 = 0; i2 < 4; ++i2)
                #pragma unroll
                for (int j2 = 0; j2 < 4; ++j2)
                    acc[i2][j2] += a_[i2] * b_[j2];
        }
        __syncthreads();
    }

    #pragma unroll
    for (int i2 = 0; i2 < 4; ++i2) {
        const int r = rowBase + ty * 4 + i2;
        #pragma unroll
        for (int j2 = 0; j2 < 4; ++j2) {
            const int d = colBase + tx * 4 + j2;
            float v = acc[i2][j2];
            if (EPI) {
                const int t = r & (T_DIM - 1);
                v *= S[(size_t)(2 * d + (t >> 10)) * D_DIM + (t & 1023)];
            }
            C[(size_t)r * 1024 + d] = v;
        }
    }
}

// ---------------------------------------------------------------------------
// K3: in-place scan over t on m[T,D]:
//   S[1] = m[1]; S[t] = g*S[t-1] + m[t] (t>=2); S[0] = m[1]  (m[0] unused)
// ---------------------------------------------------------------------------
__global__ __launch_bounds__(256) void k_scan(float* __restrict__ m) {
    const int d = blockIdx.x * 256 + threadIdx.x;   // 1024 columns
    float r = m[D_DIM + d];        // m[1][d]
    m[d] = r;                      // S[0] = m[1]; m[1] already equals S[1]
    #pragma unroll 4
    for (int t = 2; t < T_DIM; ++t) {
        r = GAMMA_F * r + m[(size_t)t * D_DIM + d];
        m[(size_t)t * D_DIM + d] = r;
    }
}

// ---------------------------------------------------------------------------
extern "C" void kernel_launch(void* const* d_in, const int* in_sizes, int n_in,
                              void* d_out, int out_size, void* d_ws, size_t ws_size,
                              hipStream_t stream) {
    const float* x  = (const float*)d_in[0];   // [4,2048,1024]
    const float* Wq = (const float*)d_in[1];   // [1024,1024]
    const float* Wk = (const float*)d_in[2];
    const float* Wv = (const float*)d_in[3];
    float* out = (float*)d_out;                // [4,2048,1024] fp32
    float* ws  = (float*)d_ws;

    float* wv_sum = ws;                         // 1024 floats
    float* y      = ws + 16384;                 // [2048,1024]
    float* m      = y + (size_t)T_DIM * D_DIM;  // [2048,1024] -> becomes S

    const int M_q = in_sizes[0] / D_DIM;        // B*T = 8192

    k_wvsum<<<D_DIM, 256, 0, stream>>>(Wv, wv_sum);
    k_vsum_y<<<T_DIM, 256, 0, stream>>>(x, wv_sum, y);

    dim3 gm(T_DIM / 64, D_DIM / 64);
    k_gemm<0><<<gm, 256, 0, stream>>>(y, Wk, m, nullptr);

    k_scan<<<D_DIM / 256, 256, 0, stream>>>(m);

    dim3 gq(M_q / 64, D_DIM / 64);
    k_gemm<1><<<gq, 256, 0, stream>>>(x, Wq, out, m);
}

// Round 3
// 109.489 us; speedup vs baseline: 5.7523x; 5.7523x over previous
//
#include <hip/hip_runtime.h>
#include <hip/hip_bf16.h>
#include <cstddef>

#define T_DIM 2048
#define D_DIM 1024
#define GAMMA_F 0.96875f

typedef __attribute__((ext_vector_type(8))) short bf16x8;
typedef __attribute__((ext_vector_type(4))) float f32x4;

#define AS1 __attribute__((address_space(1)))
#define AS3 __attribute__((address_space(3)))

// ---------------------------------------------------------------------------
// K0: wv_sum[i] = sum_d Wv[i][d]
// ---------------------------------------------------------------------------
__global__ __launch_bounds__(256) void k_wvsum(const float* __restrict__ Wv,
                                               float* __restrict__ wv_sum) {
    __shared__ float red[4];
    const int i = blockIdx.x;
    const int tid = threadIdx.x;
    const float* row = Wv + (size_t)i * D_DIM;
    float p = 0.f;
    for (int c = tid; c < D_DIM; c += 256) p += row[c];
    for (int o = 32; o; o >>= 1) p += __shfl_down(p, o);
    if ((tid & 63) == 0) red[tid >> 6] = p;
    __syncthreads();
    if (tid == 0) wv_sum[i] = red[0] + red[1] + red[2] + red[3];
}

// ---------------------------------------------------------------------------
// K1: per t: vsum[b] = x[b,t,:].wv_sum;  y[t,i] = sum_b x[b,t,i]*vsum[b]
// Emits bf16: y_bf16 [T,D] and x_bf16 [B*T,D]. One pass over x.
// ---------------------------------------------------------------------------
__global__ __launch_bounds__(256) void k_vsum_y(const float* __restrict__ x,
                                                const float* __restrict__ wv_sum,
                                                __hip_bfloat16* __restrict__ yb,
                                                __hip_bfloat16* __restrict__ xb) {
    __shared__ float xs[4][D_DIM];
    __shared__ float red[4][4];   // [wave][b]
    const int t = blockIdx.x;
    const int tid = threadIdx.x;
    const int lane = tid & 63, wv = tid >> 6;

    #pragma unroll
    for (int b = 0; b < 4; ++b) {
        const float* xr = x + ((size_t)b * T_DIM + t) * D_DIM;
        for (int c = tid; c < D_DIM; c += 256) xs[b][c] = xr[c];
    }
    __syncthreads();

    #pragma unroll
    for (int b = 0; b < 4; ++b) {
        float p = 0.f;
        for (int c = tid; c < D_DIM; c += 256) p += xs[b][c] * wv_sum[c];
        for (int o = 32; o; o >>= 1) p += __shfl_down(p, o);
        if (lane == 0) red[wv][b] = p;
    }
    __syncthreads();

    float vs[4];
    #pragma unroll
    for (int b = 0; b < 4; ++b)
        vs[b] = red[0][b] + red[1][b] + red[2][b] + red[3][b];

    for (int i = tid; i < D_DIM; i += 256) {
        float acc = 0.f;
        #pragma unroll
        for (int b = 0; b < 4; ++b) {
            acc += xs[b][i] * vs[b];
            xb[((size_t)b * T_DIM + t) * D_DIM + i] = __float2bfloat16(xs[b][i]);
        }
        yb[(size_t)t * D_DIM + i] = __float2bfloat16(acc);
    }
}

// ---------------------------------------------------------------------------
// K2: W [K=1024, N=1024] fp32 -> WT [N,K] bf16 (transpose via LDS tile)
// ---------------------------------------------------------------------------
__global__ __launch_bounds__(256) void k_cvtWT(const float* __restrict__ W,
                                               __hip_bfloat16* __restrict__ WT) {
    __shared__ float tile[32][33];
    const int tx = threadIdx.x & 31, ty = threadIdx.x >> 5;  // 32 x 8
    const int kb = blockIdx.x * 32, nb = blockIdx.y * 32;
    #pragma unroll
    for (int r = 0; r < 4; ++r)
        tile[ty + 8 * r][tx] = W[(size_t)(kb + ty + 8 * r) * 1024 + nb + tx];
    __syncthreads();
    #pragma unroll
    for (int r = 0; r < 4; ++r)
        WT[(size_t)(nb + ty + 8 * r) * 1024 + kb + tx] =
            __float2bfloat16(tile[tx][ty + 8 * r]);
}

// ---------------------------------------------------------------------------
// K3: bf16 MFMA GEMM  C[M,1024] = A[M,1024] @ B[1024,1024]
// A: [M,K] bf16 row-major. BT: [N,K] bf16. C fp32. 128x128 tile, BK=32,
// 4 waves (2x2), 16x16x32 MFMA, global_load_lds width 16 (m97 structure).
// EPI=1 fuses: out[r,d] = acc * S[2d + (t>>10)][t&1023], t = r & 2047.
// ---------------------------------------------------------------------------
template <int EPI>
__global__ __launch_bounds__(256) void k_mfma_gemm(const ushort* __restrict__ A,
                                                   const ushort* __restrict__ BT,
                                                   float* __restrict__ C,
                                                   const float* __restrict__ S) {
    __shared__ ushort As[128][32];   // 8 KB
    __shared__ ushort Bs[128][32];   // 8 KB
    const int tid = threadIdx.x;
    const int lane = tid & 63;
    const int wid = tid >> 6;
    const int wr = wid >> 1, wc = wid & 1;
    const int rowBase = blockIdx.x * 128;
    const int colBase = blockIdx.y * 128;

    f32x4 acc[4][4] = {};

    for (int kb = 0; kb < 1024; kb += 32) {
        #pragma unroll
        for (int q = 0; q < 2; ++q) {
            const int e = tid * 8 + q * 2048;         // linear bf16 element
            const int r = e >> 5, c = e & 31;
            __builtin_amdgcn_global_load_lds(
                (const AS1 void*)(A + (size_t)(rowBase + r) * 1024 + kb + c),
                (AS3 void*)&As[r][c], 16, 0, 0);
            __builtin_amdgcn_global_load_lds(
                (const AS1 void*)(BT + (size_t)(colBase + r) * 1024 + kb + c),
                (AS3 void*)&Bs[r][c], 16, 0, 0);
        }
        __syncthreads();

        bf16x8 af[4], bfv[4];
        #pragma unroll
        for (int mi = 0; mi < 4; ++mi)
            af[mi] = *(const bf16x8*)&As[wr * 64 + mi * 16 + (lane & 15)][(lane >> 4) * 8];
        #pragma unroll
        for (int ni = 0; ni < 4; ++ni)
            bfv[ni] = *(const bf16x8*)&Bs[wc * 64 + ni * 16 + (lane & 15)][(lane >> 4) * 8];

        #pragma unroll
        for (int mi = 0; mi < 4; ++mi)
            #pragma unroll
            for (int ni = 0; ni < 4; ++ni)
                acc[mi][ni] = __builtin_amdgcn_mfma_f32_16x16x32_bf16(
                    af[mi], bfv[ni], acc[mi][ni], 0, 0, 0);
        __syncthreads();
    }

    #pragma unroll
    for (int mi = 0; mi < 4; ++mi) {
        #pragma unroll
        for (int ni = 0; ni < 4; ++ni) {
            const int col = colBase + wc * 64 + ni * 16 + (lane & 15);
            #pragma unroll
            for (int q = 0; q < 4; ++q) {
                const int row = rowBase + wr * 64 + mi * 16 + (lane >> 4) * 4 + q;
                float v = acc[mi][ni][q];
                if (EPI) {
                    const int t = row & (T_DIM - 1);
                    v *= S[(size_t)(2 * col + (t >> 10)) * D_DIM + (t & 1023)];
                }
                C[(size_t)row * D_DIM + col] = v;
            }
        }
    }
}

// ---------------------------------------------------------------------------
// Parallel scan over t: S[t] = g*S[t-1] + m[t], with m[0]:=0, then S[0]=S[1].
// 64 chunks of 32 per column.
// ---------------------------------------------------------------------------
#define SC_L 32
#define SC_NC 64

__global__ __launch_bounds__(256) void k_scan1(const float* __restrict__ m,
                                               float* __restrict__ tot) {
    const int col = blockIdx.x * 64 + (threadIdx.x & 63);
    const int ch  = blockIdx.y * 4 + (threadIdx.x >> 6);
    const int t0 = ch * SC_L;
    float r = 0.f;
    #pragma unroll 4
    for (int k = 0; k < SC_L; ++k) {
        const int t = t0 + k;
        const float a = (t == 0) ? 0.f : m[(size_t)t * D_DIM + col];
        r = GAMMA_F * r + a;
    }
    tot[(size_t)ch * D_DIM + col] = r;
}

__global__ __launch_bounds__(256) void k_scan2(float* __restrict__ m,
                                               const float* __restrict__ tot) {
    const int col = blockIdx.x * 64 + (threadIdx.x & 63);
    const int ch  = blockIdx.y * 4 + (threadIdx.x >> 6);
    const int t0 = ch * SC_L;

    float gL = 1.f;
    #pragma unroll
    for (int i = 0; i < SC_L; ++i) gL *= GAMMA_F;

    // carry = S[t0-1] = sum_{j<ch} (g^L)^(ch-1-j) * tot[j]
    float carry = 0.f, f = 1.f;          // FIX: f starts at 1 (was gL — off by g^L)
    for (int j = ch - 1; j >= 0; --j) {
        carry += f * tot[(size_t)j * D_DIM + col];
        f *= gL;
    }

    float r = carry, s1 = 0.f;
    #pragma unroll 4
    for (int k = 0; k < SC_L; ++k) {
        const int t = t0 + k;
        const float a = (t == 0) ? 0.f : m[(size_t)t * D_DIM + col];
        r = GAMMA_F * r + a;
        m[(size_t)t * D_DIM + col] = r;
        if (t == 1) s1 = r;
    }
    if (ch == 0) m[col] = s1;   // S[0] = S[1]
}

// ---------------------------------------------------------------------------
extern "C" void kernel_launch(void* const* d_in, const int* in_sizes, int n_in,
                              void* d_out, int out_size, void* d_ws, size_t ws_size,
                              hipStream_t stream) {
    const float* x  = (const float*)d_in[0];   // [4,2048,1024]
    const float* Wq = (const float*)d_in[1];
    const float* Wk = (const float*)d_in[2];
    const float* Wv = (const float*)d_in[3];
    float* out = (float*)d_out;                // [4,2048,1024] fp32
    char* ws = (char*)d_ws;

    __hip_bfloat16* xb  = (__hip_bfloat16*)(ws);                    // 16 MB
    float*          m   = (float*)(ws + (16u << 20));               //  8 MB
    __hip_bfloat16* yb  = (__hip_bfloat16*)(ws + (24u << 20));      //  4 MB
    __hip_bfloat16* WT  = (__hip_bfloat16*)(ws + (28u << 20));      //  2 MB
    float* wv_sum = m;                 // m row 0: free until gemm<0> writes it
    float* tot    = (float*)yb;        // y consumed before scan needs tot

    const int M_q = in_sizes[0] / D_DIM;       // 8192

    k_wvsum<<<D_DIM, 256, 0, stream>>>(Wv, wv_sum);
    k_vsum_y<<<T_DIM, 256, 0, stream>>>(x, wv_sum, yb, xb);

    dim3 gW(32, 32);
    k_cvtWT<<<gW, 256, 0, stream>>>(Wk, WT);

    dim3 gm(T_DIM / 128, D_DIM / 128);
    k_mfma_gemm<0><<<gm, 256, 0, stream>>>((const ushort*)yb, (const ushort*)WT, m, nullptr);

    dim3 gs(D_DIM / 64, SC_NC / 4);
    k_scan1<<<gs, 256, 0, stream>>>(m, tot);
    k_scan2<<<gs, 256, 0, stream>>>(m, tot);

    k_cvtWT<<<gW, 256, 0, stream>>>(Wq, WT);

    dim3 gq(M_q / 128, D_DIM / 128);
    k_mfma_gemm<1><<<gq, 256, 0, stream>>>((const ushort*)xb, (const ushort*)WT, out, m);
}